// Round 5
// baseline (752.478 us; speedup 1.0000x reference)
//
#include <hip/hip_runtime.h>

#define T_DIM 32
#define N_NODES 10000
#define E_EDGES 160000
#define NB_AGG 2500            // node-groups of 4 per t-slice
#define EPAD 240000            // padded-CSR capacity (rows padded to mult. of 8)
#define NBLK 2048              // k_layer grid: 8 blocks/CU, all co-resident
#define NBLK_XCD 256           // blocks per XCD (NBLK/8)

typedef float f32x4 __attribute__((ext_vector_type(4)));

// Fused: zero padded edge array, zero deg/count, detect index width.
// flag=1 -> int32 edge_index layout, flag=0 -> int64 (odd int32 words all 0).
__global__ __launch_bounds__(256) void k_prep(int2* __restrict__ epair,
                                              float* __restrict__ deg,
                                              int* __restrict__ count,
                                              const int* __restrict__ ei,
                                              int* __restrict__ flag) {
    int i = blockIdx.x * 256 + threadIdx.x;
    if (i < EPAD) epair[i] = make_int2(0, 0);
    if (i < N_NODES) { deg[i] = 0.f; count[i] = 0; }
    if (blockIdx.x == 0) {
        __shared__ int s_any;
        if (threadIdx.x == 0) s_any = 0;
        __syncthreads();
        if (ei[2 * threadIdx.x + 1] != 0) atomicOr(&s_any, 1);
        __syncthreads();
        if (threadIdx.x == 0) *flag = s_any;
    }
}

__device__ __forceinline__ int load_src(const int* ei, int e, int i32layout) {
    return i32layout ? ei[e] : ei[2 * e];
}
__device__ __forceinline__ int load_dst(const int* ei, int e, int i32layout) {
    return i32layout ? ei[E_EDGES + e] : ei[2 * E_EDGES + 2 * e];
}

__global__ __launch_bounds__(256) void k_deg(const int* __restrict__ ei,
                                             const float* __restrict__ ew,
                                             float* __restrict__ deg, int* __restrict__ count,
                                             const int* __restrict__ flag) {
    int e = blockIdx.x * 256 + threadIdx.x;
    int fl = *flag;
    if (e < E_EDGES) {
        int d = load_dst(ei, e, fl);
        atomicAdd(&deg[d], ew[e]);
        atomicAdd(&count[d], 1);
    }
}

// single-block exclusive prefix sum over PADDED counts -> row_ptr / cursor.
// Rows padded to multiples of 8 edges so the gather loop has no remainder.
__global__ __launch_bounds__(1024) void k_scan(const int* __restrict__ count,
                                               int* __restrict__ row_ptr,
                                               int* __restrict__ cursor) {
    __shared__ int sdata[1024];
    __shared__ int s_run;
    if (threadIdx.x == 0) s_run = 0;
    __syncthreads();
    for (int base = 0; base < N_NODES; base += 1024) {
        int i = base + (int)threadIdx.x;
        int v = (i < N_NODES) ? ((count[i] + 7) & ~7) : 0;
        sdata[threadIdx.x] = v;
        __syncthreads();
        for (int off = 1; off < 1024; off <<= 1) {
            int t = (threadIdx.x >= (unsigned)off) ? sdata[threadIdx.x - off] : 0;
            __syncthreads();
            sdata[threadIdx.x] += t;
            __syncthreads();
        }
        int incl = sdata[threadIdx.x];
        int run = s_run;
        __syncthreads();
        if (i < N_NODES) { int ex = run + incl - v; row_ptr[i] = ex; cursor[i] = ex; }
        if (threadIdx.x == 1023) s_run = run + incl;
        __syncthreads();
    }
    if (threadIdx.x == 0) row_ptr[N_NODES] = s_run;
}

// fill CSR with norm computed inline (dinv folded in; rsqrtf validated R3)
__global__ __launch_bounds__(256) void k_fill(const int* __restrict__ ei,
                                              const float* __restrict__ ew,
                                              const float* __restrict__ deg,
                                              int* __restrict__ cursor,
                                              int2* __restrict__ epair,
                                              const int* __restrict__ flag) {
    int e = blockIdx.x * 256 + threadIdx.x;
    int fl = *flag;
    if (e < E_EDGES) {
        int s = load_src(ei, e, fl);
        int d = load_dst(ei, e, fl);
        float ds_ = deg[s], dd = deg[d];
        float nrm = ((ds_ > 0.f) ? rsqrtf(ds_) : 0.f) * ew[e] *
                    ((dd > 0.f) ? rsqrtf(dd) : 0.f);
        int pos = atomicAdd(&cursor[d], 1);
        epair[pos] = make_int2(s, __float_as_int(nrm));
    }
}

// Fused layer: out[t,n,:] = (relu?)( (A * hin)[t,n,:] @ W + bias ).
// XCD-partitioned: block b runs on XCD (b&7) [dispatch round-robin, m09];
// XCD j owns t-slices 4j..4j+3, processed one at a time -> the 2.56 MB
// per-t gather slice stays resident in that XCD's 4 MB L2.
// W staged in LDS (16 KB; column reads are 2-way bank-aliased = free).
// Gather loop: padded CSR chunks of 8 edges, next chunk's metadata
// prefetched before current chunk's gathers. Output stores non-temporal
// so the write stream doesn't evict the L2 gather slice.
__global__ __launch_bounds__(256) void k_layer(const float* __restrict__ hin,
                                               float* __restrict__ out,
                                               const int* __restrict__ row_ptr,
                                               const int2* __restrict__ epair,
                                               const float* __restrict__ W,
                                               const float* __restrict__ bias,
                                               int relu) {
    __shared__ float sW[64 * 64];
    __shared__ float srow[256];
    int lane = threadIdx.x & 63;
    int wave = threadIdx.x >> 6;
    // stage W: 1024 float4s over 256 threads
    {
        const f32x4* Wg = (const f32x4*)W;
        f32x4* Wl = (f32x4*)sW;
#pragma unroll
        for (int i = 0; i < 4; ++i) Wl[threadIdx.x + i * 256] = Wg[threadIdx.x + i * 256];
    }
    float bv = bias[lane];
    __syncthreads();

    int xcd = blockIdx.x & 7;
    int lb  = blockIdx.x >> 3;          // 0..255 within this XCD
#pragma unroll 1
    for (int i = 0; i < 4; ++i) {
        int t = xcd * 4 + i;
        const float* hb = hin + (size_t)t * (N_NODES * 64);
        float* ob = out + (size_t)t * (N_NODES * 64);
#pragma unroll 1
        for (int nb = lb; nb < NB_AGG; nb += NBLK_XCD) {
            int n = nb * 4 + wave;
            int e = row_ptr[n], end = row_ptr[n + 1];
            float a0 = 0.f, a1 = 0.f, a2 = 0.f, a3 = 0.f;
            if (e < end) {
                int4 q0 = *(const int4*)(epair + e);
                int4 q1 = *(const int4*)(epair + e + 2);
                int4 q2 = *(const int4*)(epair + e + 4);
                int4 q3 = *(const int4*)(epair + e + 6);
                for (e += 8; e < end; e += 8) {
                    int4 p0 = *(const int4*)(epair + e);       // prefetch next
                    int4 p1 = *(const int4*)(epair + e + 2);
                    int4 p2 = *(const int4*)(epair + e + 4);
                    int4 p3 = *(const int4*)(epair + e + 6);
                    float h0 = hb[(size_t)q0.x * 64 + lane];
                    float h1 = hb[(size_t)q0.z * 64 + lane];
                    float h2 = hb[(size_t)q1.x * 64 + lane];
                    float h3 = hb[(size_t)q1.z * 64 + lane];
                    float h4 = hb[(size_t)q2.x * 64 + lane];
                    float h5 = hb[(size_t)q2.z * 64 + lane];
                    float h6 = hb[(size_t)q3.x * 64 + lane];
                    float h7 = hb[(size_t)q3.z * 64 + lane];
                    a0 = fmaf(__int_as_float(q0.y), h0, a0);
                    a1 = fmaf(__int_as_float(q0.w), h1, a1);
                    a2 = fmaf(__int_as_float(q1.y), h2, a2);
                    a3 = fmaf(__int_as_float(q1.w), h3, a3);
                    a0 = fmaf(__int_as_float(q2.y), h4, a0);
                    a1 = fmaf(__int_as_float(q2.w), h5, a1);
                    a2 = fmaf(__int_as_float(q3.y), h6, a2);
                    a3 = fmaf(__int_as_float(q3.w), h7, a3);
                    q0 = p0; q1 = p1; q2 = p2; q3 = p3;
                }
                float h0 = hb[(size_t)q0.x * 64 + lane];
                float h1 = hb[(size_t)q0.z * 64 + lane];
                float h2 = hb[(size_t)q1.x * 64 + lane];
                float h3 = hb[(size_t)q1.z * 64 + lane];
                float h4 = hb[(size_t)q2.x * 64 + lane];
                float h5 = hb[(size_t)q2.z * 64 + lane];
                float h6 = hb[(size_t)q3.x * 64 + lane];
                float h7 = hb[(size_t)q3.z * 64 + lane];
                a0 = fmaf(__int_as_float(q0.y), h0, a0);
                a1 = fmaf(__int_as_float(q0.w), h1, a1);
                a2 = fmaf(__int_as_float(q1.y), h2, a2);
                a3 = fmaf(__int_as_float(q1.w), h3, a3);
                a0 = fmaf(__int_as_float(q2.y), h4, a0);
                a1 = fmaf(__int_as_float(q2.w), h5, a1);
                a2 = fmaf(__int_as_float(q3.y), h6, a2);
                a3 = fmaf(__int_as_float(q3.w), h7, a3);
            }
            srow[threadIdx.x] = (a0 + a1) + (a2 + a3);
            // same-wave LDS write->read: ordered by lgkmcnt, no barrier
            const f32x4* sr = (const f32x4*)(srow + wave * 64);
            float o = bv;
#pragma unroll
            for (int k4 = 0; k4 < 16; ++k4) {
                f32x4 v = sr[k4];                       // broadcast read
                o = fmaf(v.x, sW[(4 * k4 + 0) * 64 + lane], o);
                o = fmaf(v.y, sW[(4 * k4 + 1) * 64 + lane], o);
                o = fmaf(v.z, sW[(4 * k4 + 2) * 64 + lane], o);
                o = fmaf(v.w, sW[(4 * k4 + 3) * 64 + lane], o);
            }
            if (relu) o = fmaxf(o, 0.f);
            __builtin_nontemporal_store(o, &ob[(size_t)n * 64 + lane]);
        }
    }
}

// fallback-path copy (only used when workspace is too small for the h buffer)
__global__ __launch_bounds__(256) void k_copy(const f32x4* __restrict__ src,
                                              f32x4* __restrict__ dst, int n4) {
    int i = blockIdx.x * 256 + threadIdx.x;
    int stride = gridDim.x * 256;
    for (; i < n4; i += stride) dst[i] = src[i];
}

extern "C" void kernel_launch(void* const* d_in, const int* in_sizes, int n_in,
                              void* d_out, int out_size, void* d_ws, size_t ws_size,
                              hipStream_t stream) {
    const float* x  = (const float*)d_in[0];
    const int* ei   = (const int*)d_in[1];
    const float* ew = (const float*)d_in[2];
    const float* W1 = (const float*)d_in[3];
    const float* b1 = (const float*)d_in[4];
    const float* W2 = (const float*)d_in[5];
    const float* b2 = (const float*)d_in[6];
    float* out = (float*)d_out;
    (void)in_sizes; (void)n_in; (void)out_size;

    char* w = (char*)d_ws;
    size_t off = 0;
    auto alloc = [&](size_t bytes) {
        char* p = w + off;
        off = (off + bytes + 255) & ~(size_t)255;
        return p;
    };
    int*   flag   = (int*)  alloc(4);
    float* deg    = (float*)alloc(N_NODES * 4);
    int*   count  = (int*)  alloc(N_NODES * 4);
    int*   rowptr = (int*)  alloc((N_NODES + 1) * 4);
    int*   cursor = (int*)  alloc(N_NODES * 4);
    int2*  epair  = (int2*) alloc((size_t)EPAD * 8);

    const size_t hbytes = (size_t)T_DIM * N_NODES * 64 * 4;   // 81.92 MB
    bool big_ws = (ws_size >= off + hbytes);
    float* hbuf = big_ws ? (float*)alloc(hbytes) : nullptr;

    // ---- CSR build ----
    k_prep<<<(EPAD + 255) / 256, 256, 0, stream>>>(epair, deg, count, ei, flag);
    k_deg<<<(E_EDGES + 255) / 256, 256, 0, stream>>>(ei, ew, deg, count, flag);
    k_scan<<<1, 1024, 0, stream>>>(count, rowptr, cursor);
    k_fill<<<(E_EDGES + 255) / 256, 256, 0, stream>>>(ei, ew, deg, cursor, epair, flag);

    if (big_ws) {
        k_layer<<<NBLK, 256, 0, stream>>>(x, hbuf, rowptr, epair, W1, b1, 1);
        k_layer<<<NBLK, 256, 0, stream>>>(hbuf, out, rowptr, epair, W2, b2, 0);
    } else {
        // xscr reuses d_in[0]: x fully consumed by layer 1; harness restores
        // d_in from pristine before every launch.
        float* xscr = (float*)d_in[0];
        k_layer<<<NBLK, 256, 0, stream>>>(x, out, rowptr, epair, W1, b1, 1);
        k_layer<<<NBLK, 256, 0, stream>>>(out, xscr, rowptr, epair, W2, b2, 0);
        int n4 = (int)(hbytes / 16);
        k_copy<<<2048, 256, 0, stream>>>((const f32x4*)xscr, (f32x4*)out, n4);
    }
}

// Round 6
// 474.788 us; speedup vs baseline: 1.5849x; 1.5849x over previous
//
#include <hip/hip_runtime.h>

#define T_DIM 32
#define N_NODES 10000
#define E_EDGES 160000
#define NB_AGG 2500            // node-groups of 4 per t-slice
#define EPAD 240000            // padded-CSR capacity (rows padded to mult. of 8)
#define NBLK 2048              // k_layer grid
#define NBLK_XCD 256           // blocks per XCD (NBLK/8)

typedef float f32x4 __attribute__((ext_vector_type(4)));

// Fused: zero padded edge array, zero deg/count, detect index width.
// flag=1 -> int32 edge_index layout, flag=0 -> int64 (odd int32 words all 0).
__global__ __launch_bounds__(256) void k_prep(int2* __restrict__ epair,
                                              float* __restrict__ deg,
                                              int* __restrict__ count,
                                              const int* __restrict__ ei,
                                              int* __restrict__ flag) {
    int i = blockIdx.x * 256 + threadIdx.x;
    if (i < EPAD) epair[i] = make_int2(0, 0);
    if (i < N_NODES) { deg[i] = 0.f; count[i] = 0; }
    if (blockIdx.x == 0) {
        __shared__ int s_any;
        if (threadIdx.x == 0) s_any = 0;
        __syncthreads();
        if (ei[2 * threadIdx.x + 1] != 0) atomicOr(&s_any, 1);
        __syncthreads();
        if (threadIdx.x == 0) *flag = s_any;
    }
}

__device__ __forceinline__ int load_src(const int* ei, int e, int i32layout) {
    return i32layout ? ei[e] : ei[2 * e];
}
__device__ __forceinline__ int load_dst(const int* ei, int e, int i32layout) {
    return i32layout ? ei[E_EDGES + e] : ei[2 * E_EDGES + 2 * e];
}

__global__ __launch_bounds__(256) void k_deg(const int* __restrict__ ei,
                                             const float* __restrict__ ew,
                                             float* __restrict__ deg, int* __restrict__ count,
                                             const int* __restrict__ flag) {
    int e = blockIdx.x * 256 + threadIdx.x;
    int fl = *flag;
    if (e < E_EDGES) {
        int d = load_dst(ei, e, fl);
        atomicAdd(&deg[d], ew[e]);
        atomicAdd(&count[d], 1);
    }
}

// single-block exclusive prefix sum over PADDED counts -> row_ptr / cursor.
__global__ __launch_bounds__(1024) void k_scan(const int* __restrict__ count,
                                               int* __restrict__ row_ptr,
                                               int* __restrict__ cursor) {
    __shared__ int sdata[1024];
    __shared__ int s_run;
    if (threadIdx.x == 0) s_run = 0;
    __syncthreads();
    for (int base = 0; base < N_NODES; base += 1024) {
        int i = base + (int)threadIdx.x;
        int v = (i < N_NODES) ? ((count[i] + 7) & ~7) : 0;
        sdata[threadIdx.x] = v;
        __syncthreads();
        for (int off = 1; off < 1024; off <<= 1) {
            int t = (threadIdx.x >= (unsigned)off) ? sdata[threadIdx.x - off] : 0;
            __syncthreads();
            sdata[threadIdx.x] += t;
            __syncthreads();
        }
        int incl = sdata[threadIdx.x];
        int run = s_run;
        __syncthreads();
        if (i < N_NODES) { int ex = run + incl - v; row_ptr[i] = ex; cursor[i] = ex; }
        if (threadIdx.x == 1023) s_run = run + incl;
        __syncthreads();
    }
    if (threadIdx.x == 0) row_ptr[N_NODES] = s_run;
}

__global__ __launch_bounds__(256) void k_fill(const int* __restrict__ ei,
                                              const float* __restrict__ ew,
                                              const float* __restrict__ deg,
                                              int* __restrict__ cursor,
                                              int2* __restrict__ epair,
                                              const int* __restrict__ flag) {
    int e = blockIdx.x * 256 + threadIdx.x;
    int fl = *flag;
    if (e < E_EDGES) {
        int s = load_src(ei, e, fl);
        int d = load_dst(ei, e, fl);
        float ds_ = deg[s], dd = deg[d];
        float nrm = ((ds_ > 0.f) ? rsqrtf(ds_) : 0.f) * ew[e] *
                    ((dd > 0.f) ? rsqrtf(dd) : 0.f);
        int pos = atomicAdd(&cursor[d], 1);
        epair[pos] = make_int2(s, __float_as_int(nrm));
    }
}

#define GATHER8(M0, M1, M2, M3, H)                                  \
    H##0 = hb[(size_t)(M0).x * 64 + lane];                          \
    H##1 = hb[(size_t)(M0).z * 64 + lane];                          \
    H##2 = hb[(size_t)(M1).x * 64 + lane];                          \
    H##3 = hb[(size_t)(M1).z * 64 + lane];                          \
    H##4 = hb[(size_t)(M2).x * 64 + lane];                          \
    H##5 = hb[(size_t)(M2).z * 64 + lane];                          \
    H##6 = hb[(size_t)(M3).x * 64 + lane];                          \
    H##7 = hb[(size_t)(M3).z * 64 + lane];

#define FMA8(M0, M1, M2, M3, H)                                     \
    a0 = fmaf(__int_as_float((M0).y), H##0, a0);                    \
    a1 = fmaf(__int_as_float((M0).w), H##1, a1);                    \
    a2 = fmaf(__int_as_float((M1).y), H##2, a2);                    \
    a3 = fmaf(__int_as_float((M1).w), H##3, a3);                    \
    a0 = fmaf(__int_as_float((M2).y), H##4, a0);                    \
    a1 = fmaf(__int_as_float((M2).w), H##5, a1);                    \
    a2 = fmaf(__int_as_float((M3).y), H##6, a2);                    \
    a3 = fmaf(__int_as_float((M3).w), H##7, a3);

// Fused layer: out[t,n,:] = (relu?)( (A * hin)[t,n,:] @ W + bias ).
// XCD-pinned t-slices (R5: FETCH = near-ideal 155 MB). R6: edge metadata is
// wave-uniform -> readfirstlane + scalar loads (SGPR-resident, frees VGPRs &
// VMEM slots); gathers software-pipelined one chunk ahead (meta two ahead) so
// ~16-24 loads are in flight per wave at every FMA wait.
__global__ __launch_bounds__(256) void k_layer(const float* __restrict__ hin,
                                               float* __restrict__ out,
                                               const int* __restrict__ row_ptr,
                                               const int4* __restrict__ emeta,
                                               const float* __restrict__ W,
                                               const float* __restrict__ bias,
                                               int relu) {
    __shared__ float sW[64 * 64];
    __shared__ float srow[256];
    int lane = threadIdx.x & 63;
    int wave = threadIdx.x >> 6;
    {
        const f32x4* Wg = (const f32x4*)W;
        f32x4* Wl = (f32x4*)sW;
#pragma unroll
        for (int i = 0; i < 4; ++i) Wl[threadIdx.x + i * 256] = Wg[threadIdx.x + i * 256];
    }
    float bv = bias[lane];
    __syncthreads();

    int xcd = blockIdx.x & 7;
    int lb  = blockIdx.x >> 3;          // 0..255 within this XCD
#pragma unroll 1
    for (int i = 0; i < 4; ++i) {
        int t = xcd * 4 + i;
        const float* hb = hin + (size_t)t * (N_NODES * 64);
        float* ob = out + (size_t)t * (N_NODES * 64);
#pragma unroll 1
        for (int nb = lb; nb < NB_AGG; nb += NBLK_XCD) {
            int n = nb * 4 + wave;
            int un = __builtin_amdgcn_readfirstlane(n);     // wave-uniform -> SGPR
            int e   = row_ptr[un];                          // s_load
            int end = row_ptr[un + 1];
            float a0 = 0.f, a1 = 0.f, a2 = 0.f, a3 = 0.f;
            if (e < end) {
                // stage A: chunk 0 meta (scalar) + gathers issued
                int4 mA0 = emeta[(e >> 1) + 0];
                int4 mA1 = emeta[(e >> 1) + 1];
                int4 mA2 = emeta[(e >> 1) + 2];
                int4 mA3 = emeta[(e >> 1) + 3];
                float hA0, hA1, hA2, hA3, hA4, hA5, hA6, hA7;
                GATHER8(mA0, mA1, mA2, mA3, hA)
                e += 8;
                if (e < end) {
                    // stage B meta
                    int4 mB0 = emeta[(e >> 1) + 0];
                    int4 mB1 = emeta[(e >> 1) + 1];
                    int4 mB2 = emeta[(e >> 1) + 2];
                    int4 mB3 = emeta[(e >> 1) + 3];
                    for (e += 8; e < end; e += 8) {
                        int4 mC0 = emeta[(e >> 1) + 0];      // meta 2 ahead
                        int4 mC1 = emeta[(e >> 1) + 1];
                        int4 mC2 = emeta[(e >> 1) + 2];
                        int4 mC3 = emeta[(e >> 1) + 3];
                        float hB0, hB1, hB2, hB3, hB4, hB5, hB6, hB7;
                        GATHER8(mB0, mB1, mB2, mB3, hB)      // issue chunk c
                        FMA8(mA0, mA1, mA2, mA3, hA)         // consume c-1
                        mA0 = mB0; mA1 = mB1; mA2 = mB2; mA3 = mB3;
                        mB0 = mC0; mB1 = mC1; mB2 = mC2; mB3 = mC3;
                        hA0 = hB0; hA1 = hB1; hA2 = hB2; hA3 = hB3;
                        hA4 = hB4; hA5 = hB5; hA6 = hB6; hA7 = hB7;
                    }
                    // drain: chunk (mB) gathers + pending FMA(mA,hA)
                    float hB0, hB1, hB2, hB3, hB4, hB5, hB6, hB7;
                    GATHER8(mB0, mB1, mB2, mB3, hB)
                    FMA8(mA0, mA1, mA2, mA3, hA)
                    mA0 = mB0; mA1 = mB1; mA2 = mB2; mA3 = mB3;
                    hA0 = hB0; hA1 = hB1; hA2 = hB2; hA3 = hB3;
                    hA4 = hB4; hA5 = hB5; hA6 = hB6; hA7 = hB7;
                }
                FMA8(mA0, mA1, mA2, mA3, hA)
            }
            srow[threadIdx.x] = (a0 + a1) + (a2 + a3);
            // same-wave LDS write->read: ordered by lgkmcnt, no barrier
            const f32x4* sr = (const f32x4*)(srow + wave * 64);
            float o = bv;
#pragma unroll
            for (int k4 = 0; k4 < 16; ++k4) {
                f32x4 v = sr[k4];                       // broadcast read
                o = fmaf(v.x, sW[(4 * k4 + 0) * 64 + lane], o);
                o = fmaf(v.y, sW[(4 * k4 + 1) * 64 + lane], o);
                o = fmaf(v.z, sW[(4 * k4 + 2) * 64 + lane], o);
                o = fmaf(v.w, sW[(4 * k4 + 3) * 64 + lane], o);
            }
            if (relu) o = fmaxf(o, 0.f);
            __builtin_nontemporal_store(o, &ob[(size_t)n * 64 + lane]);
        }
    }
}

// fallback-path copy (only used when workspace is too small for the h buffer)
__global__ __launch_bounds__(256) void k_copy(const f32x4* __restrict__ src,
                                              f32x4* __restrict__ dst, int n4) {
    int i = blockIdx.x * 256 + threadIdx.x;
    int stride = gridDim.x * 256;
    for (; i < n4; i += stride) dst[i] = src[i];
}

extern "C" void kernel_launch(void* const* d_in, const int* in_sizes, int n_in,
                              void* d_out, int out_size, void* d_ws, size_t ws_size,
                              hipStream_t stream) {
    const float* x  = (const float*)d_in[0];
    const int* ei   = (const int*)d_in[1];
    const float* ew = (const float*)d_in[2];
    const float* W1 = (const float*)d_in[3];
    const float* b1 = (const float*)d_in[4];
    const float* W2 = (const float*)d_in[5];
    const float* b2 = (const float*)d_in[6];
    float* out = (float*)d_out;
    (void)in_sizes; (void)n_in; (void)out_size;

    char* w = (char*)d_ws;
    size_t off = 0;
    auto alloc = [&](size_t bytes) {
        char* p = w + off;
        off = (off + bytes + 255) & ~(size_t)255;
        return p;
    };
    int*   flag   = (int*)  alloc(4);
    float* deg    = (float*)alloc(N_NODES * 4);
    int*   count  = (int*)  alloc(N_NODES * 4);
    int*   rowptr = (int*)  alloc((N_NODES + 1) * 4);
    int*   cursor = (int*)  alloc(N_NODES * 4);
    int2*  epair  = (int2*) alloc((size_t)EPAD * 8);

    const size_t hbytes = (size_t)T_DIM * N_NODES * 64 * 4;   // 81.92 MB
    bool big_ws = (ws_size >= off + hbytes);
    float* hbuf = big_ws ? (float*)alloc(hbytes) : nullptr;

    // ---- CSR build ----
    k_prep<<<(EPAD + 255) / 256, 256, 0, stream>>>(epair, deg, count, ei, flag);
    k_deg<<<(E_EDGES + 255) / 256, 256, 0, stream>>>(ei, ew, deg, count, flag);
    k_scan<<<1, 1024, 0, stream>>>(count, rowptr, cursor);
    k_fill<<<(E_EDGES + 255) / 256, 256, 0, stream>>>(ei, ew, deg, cursor, epair, flag);

    if (big_ws) {
        k_layer<<<NBLK, 256, 0, stream>>>(x, hbuf, rowptr, (const int4*)epair, W1, b1, 1);
        k_layer<<<NBLK, 256, 0, stream>>>(hbuf, out, rowptr, (const int4*)epair, W2, b2, 0);
    } else {
        // xscr reuses d_in[0]: x fully consumed by layer 1; harness restores
        // d_in from pristine before every launch.
        float* xscr = (float*)d_in[0];
        k_layer<<<NBLK, 256, 0, stream>>>(x, out, rowptr, (const int4*)epair, W1, b1, 1);
        k_layer<<<NBLK, 256, 0, stream>>>(out, xscr, rowptr, (const int4*)epair, W2, b2, 0);
        int n4 = (int)(hbytes / 16);
        k_copy<<<2048, 256, 0, stream>>>((const f32x4*)xscr, (f32x4*)out, n4);
    }
}